// Round 17
// baseline (103.219 us; speedup 1.0000x reference)
//
#include <hip/hip_runtime.h>
#include <cstdint>

typedef __attribute__((ext_vector_type(8))) __bf16 bf16x8;
typedef __attribute__((ext_vector_type(4))) float f32x4;
typedef __attribute__((ext_vector_type(8))) short short8;
typedef __attribute__((ext_vector_type(4))) float float4v;
typedef __attribute__((ext_vector_type(4))) unsigned uint4v;
typedef __attribute__((ext_vector_type(4))) unsigned short ushort4v;

__device__ __forceinline__ unsigned short f2bf(float f) {
    unsigned u = __builtin_bit_cast(unsigned, f);
    u += 0x7fffu + ((u >> 16) & 1u);   // RNE
    return (unsigned short)(u >> 16);
}
__device__ __forceinline__ float bf2f(unsigned short s) {
    return __builtin_bit_cast(float, (unsigned)s << 16);
}
__device__ __forceinline__ f32x4 mfma_bf16(bf16x8 a, bf16x8 b, f32x4 c) {
    return __builtin_amdgcn_mfma_f32_16x16x32_bf16(a, b, c, 0, 0, 0);
}
// pack 2 f32 -> 2 bf16 in one u32 (lo = first arg), RNE
__device__ __forceinline__ unsigned pkbf(float lo, float hi) {
    unsigned r;
    asm("v_cvt_pk_bf16_f32 %0, %1, %2" : "=v"(r) : "v"(lo), "v"(hi));
    return r;
}

#define GLD16(g, l)                                                                     \
    __builtin_amdgcn_global_load_lds((const __attribute__((address_space(1))) void*)(g), \
                                     (__attribute__((address_space(3))) void*)(l), 16, 0, 0)

// ---------------------------------------------------------------------------
// fp32 -> bf16 for ALL THREE arrays in one launch (x | Wqkv | Wout).
// ---------------------------------------------------------------------------
__global__ void __launch_bounds__(256) cvt_all(const float* __restrict__ x,
                                               const float* __restrict__ wqkv,
                                               const float* __restrict__ wout,
                                               unsigned short* __restrict__ xb,
                                               unsigned short* __restrict__ wqb,
                                               unsigned short* __restrict__ wob) {
    int i = blockIdx.x * blockDim.x + threadIdx.x;
#pragma unroll
    for (int k = 0; k < 2; k++, i += 524288) {
        const float* s;
        unsigned short* d;
        int off;
        if (i < 524288)      { s = x;    d = xb;  off = i; }
        else if (i < 917504) { s = wqkv; d = wqb; off = i - 524288; }
        else                 { s = wout; d = wob; off = i - 917504; }
        const float4v* sp = (const float4v*)(s + (size_t)off * 8);
        float4v v0 = sp[0], v1 = sp[1];
        uint4v u;
        u[0] = pkbf(v0[0], v0[1]);
        u[1] = pkbf(v0[2], v0[3]);
        u[2] = pkbf(v1[0], v1[1]);
        u[3] = pkbf(v1[2], v1[3]);
        *(uint4v*)(d + (size_t)off * 8) = u;
    }
}

// ===========================================================================
// GEMM1 (QKV) v17: R16's two-barrier phase schedule (verified) + T4 counted
// vmcnt via EARLY/LATE store classes:
//   phase 1 needs B0,B1,B2 + A0 + A2 ("early 5"); phases 3-4 need A1,A3
//   ("late 2").  Store issue order per tile: B0,B1,B2 (ph1), A0,A2 (ph2),
//   A1 (ph3), A3 (ph4).
//   - tile top: vmcnt(2)+barrier  -> waits only early-5 (>=3 phases old);
//     late-2 keep flying across the boundary (never drain fresh loads).
//   - phase 2, before its mid barrier: vmcnt(5) (last tile: vmcnt(0)) ->
//     retires the 2 oldest (late-2) before any wave reaches phase-3 reads;
//     following barriers give block-wide visibility.
// Barrier placement identical to R16.
// ===========================================================================

#define STG_A(bf_, i_, t_) \
    GLD16(gA + (size_t)(i_) * 64 * 1024 + (size_t)(t_) * 64, (char*)&Asl[bf_][0] + (i_) * 8192 + w * 1024)
#define STG_B(bf_, i_, t_) \
    GLD16(gB + (size_t)(i_) * 64 * 1024 + (size_t)(t_) * 64, (char*)&Bsl[bf_][0] + (i_) * 8192 + w * 1024)

#define LDA(c_, mf_, kk_) \
    (*(const bf16x8*)((const char*)&Asl[c_][0] + (wm * 128 + (mf_) * 16 + a) * 128 + (((((kk_) << 2) + g) ^ xa) << 4)))
#define LDB(c_, nf_, kk_) \
    (*(const bf16x8*)((const char*)&Bsl[c_][0] + (wn * 48 + (nf_) * 16 + a) * 128 + (((((kk_) << 2) + g) ^ xa) << 4)))

#define MFMA12(mb_)                                                               \
    __builtin_amdgcn_s_setprio(1);                                                \
    _Pragma("unroll") for (int nf_ = 0; nf_ < 3; nf_++) {                         \
        acc[mb_][nf_]       = mfma_bf16(a0_, bfr[nf_][0], acc[mb_][nf_]);         \
        acc[mb_][nf_]       = mfma_bf16(a1_, bfr[nf_][1], acc[mb_][nf_]);         \
        acc[(mb_) + 1][nf_] = mfma_bf16(a2_, bfr[nf_][0], acc[(mb_) + 1][nf_]);   \
        acc[(mb_) + 1][nf_] = mfma_bf16(a3_, bfr[nf_][1], acc[(mb_) + 1][nf_]);   \
    }                                                                             \
    __builtin_amdgcn_s_setprio(0);

__global__ void __launch_bounds__(512, 2) gemm_qkv(const unsigned short* __restrict__ A,
                                                   const unsigned short* __restrict__ B,
                                                   const float* __restrict__ bias,
                                                   unsigned short* __restrict__ qkbuf,
                                                   unsigned short* __restrict__ vT) {
    constexpr int K = 1024;
    __shared__ __attribute__((aligned(16))) unsigned short Asl[2][256 * 64];  // 2x32KB
    __shared__ __attribute__((aligned(16))) unsigned short Bsl[2][192 * 64];  // 2x24KB
    const int tid = threadIdx.x;
    const int w = tid >> 6, lane = tid & 63;
    const int a = lane & 15, g = lane >> 4;
    const int xa = a & 7;
    const int wm = w >> 2, wn = w & 3;

    // XCD swizzle (256 blocks, bijective): 32 consecutive per XCD
    const int nfb = ((int)blockIdx.x & 7) * 32 + ((int)blockIdx.x >> 3);
    const int bx = nfb >> 4, by = nfb & 15;
    const int m0 = by * 256, n0 = bx * 192;

    f32x4 acc[8][3];
#pragma unroll
    for (int i = 0; i < 8; i++)
#pragma unroll
        for (int j = 0; j < 3; j++) acc[i][j] = (f32x4)(0.0f);

    const int rA = tid >> 3, uA = tid & 7;
    const unsigned short* gA = A + (size_t)(m0 + rA) * K + ((uA ^ (rA & 7)) << 3);
    const unsigned short* gB = B + (size_t)(n0 + rA) * K + ((uA ^ (rA & 7)) << 3);

    // prologue: stage tile 0, EARLY (B0,B1,B2,A0,A2) then LATE (A1,A3)
    STG_B(0, 0, 0); STG_B(0, 1, 0); STG_B(0, 2, 0);
    STG_A(0, 0, 0); STG_A(0, 2, 0);
    STG_A(0, 1, 0); STG_A(0, 3, 0);

    for (int t = 0; t < 16; ++t) {
        const int c = t & 1, nx = c ^ 1;
        const bool more = (t < 15);

        // tile top: early-5 of current tile landed (issued >=3 phases ago);
        // late-2 (A1,A3) may still fly — NOT needed until phase 3.
        asm volatile("s_waitcnt vmcnt(2)" ::: "memory");
        __builtin_amdgcn_s_barrier();

        bf16x8 bfr[3][2];
#pragma unroll
        for (int nf = 0; nf < 3; nf++) {
            bfr[nf][0] = LDB(c, nf, 0);
            bfr[nf][1] = LDB(c, nf, 1);
        }

        {   // phase 1: reads A rows 0-31 of wave-half (A0/A2); stores next B
            bf16x8 a0_ = LDA(c, 0, 0), a1_ = LDA(c, 0, 1);
            bf16x8 a2_ = LDA(c, 1, 0), a3_ = LDA(c, 1, 1);
            if (more) { STG_B(nx, 0, t + 1); STG_B(nx, 1, t + 1); STG_B(nx, 2, t + 1); }
            asm volatile("" ::: "memory");
            __builtin_amdgcn_s_barrier();
            asm volatile("s_waitcnt lgkmcnt(0)");
            MFMA12(0);
            __builtin_amdgcn_s_barrier();
        }
        {   // phase 2: rows 32-63; stores next A0,A2; retire late-2 (oldest)
            bf16x8 a0_ = LDA(c, 2, 0), a1_ = LDA(c, 2, 1);
            bf16x8 a2_ = LDA(c, 3, 0), a3_ = LDA(c, 3, 1);
            if (more) { STG_A(nx, 0, t + 1); STG_A(nx, 2, t + 1); }
            asm volatile("" ::: "memory");
            if (more) asm volatile("s_waitcnt vmcnt(5)" ::: "memory");
            else      asm volatile("s_waitcnt vmcnt(0)" ::: "memory");
            __builtin_amdgcn_s_barrier();
            asm volatile("s_waitcnt lgkmcnt(0)");
            MFMA12(2);
            __builtin_amdgcn_s_barrier();
        }
        {   // phase 3: rows 64-95 (A1/A3 — safe after phase-2 barriers)
            bf16x8 a0_ = LDA(c, 4, 0), a1_ = LDA(c, 4, 1);
            bf16x8 a2_ = LDA(c, 5, 0), a3_ = LDA(c, 5, 1);
            if (more) { STG_A(nx, 1, t + 1); }
            asm volatile("" ::: "memory");
            __builtin_amdgcn_s_barrier();
            asm volatile("s_waitcnt lgkmcnt(0)");
            MFMA12(4);
            __builtin_amdgcn_s_barrier();
        }
        {   // phase 4: rows 96-127
            bf16x8 a0_ = LDA(c, 6, 0), a1_ = LDA(c, 6, 1);
            bf16x8 a2_ = LDA(c, 7, 0), a3_ = LDA(c, 7, 1);
            if (more) { STG_A(nx, 3, t + 1); }
            asm volatile("" ::: "memory");
            __builtin_amdgcn_s_barrier();
            asm volatile("s_waitcnt lgkmcnt(0)");
            MFMA12(6);
            __builtin_amdgcn_s_barrier();
        }
    }

    // ---- epilogue (verified in R15/R16) ----
#pragma unroll
    for (int nf = 0; nf < 3; nf++) {
        const int cb = n0 + wn * 48 + nf * 16;
        const int col = cb + a;
        const float bv = bias[col];
        if (cb < 2048) {   // Q/K -> qk buffer (ldc = 2048)
#pragma unroll
            for (int mf = 0; mf < 8; mf++)
#pragma unroll
                for (int jr = 0; jr < 4; jr++) {
                    const int row = m0 + wm * 128 + mf * 16 + g * 4 + jr;
                    qkbuf[(size_t)row * 2048 + col] = f2bf(acc[mf][nf][jr] + bv);
                }
        } else {           // V -> vT[(b*16+h)][d][token], 4-token packs
            const int vd = col - 2048, hh = vd >> 6, dd = vd & 63;
#pragma unroll
            for (int mf = 0; mf < 8; mf++) {
                const int t0 = m0 + wm * 128 + mf * 16 + g * 4;
                const int bb = t0 >> 11, kl = t0 & 2047;
                ushort4v st;
#pragma unroll
                for (int jr = 0; jr < 4; jr++) st[jr] = f2bf(acc[mf][nf][jr] + bv);
                *(ushort4v*)(vT + ((size_t)((bb << 4) + hh) * 64 + dd) * 2048 + kl) = st;
            }
        }
    }
}

// ---------------------------------------------------------------------------
// GEMM2: C[M,N] = A[M,K]*B[N,K]^T + bias[N].  128x128 tile, BK=32, 4 waves.
// 2-PHASE double-buffered LDS (known-good structure; grid 256 = exact fill).
// ---------------------------------------------------------------------------
__global__ void __launch_bounds__(256) gemm_bt(const unsigned short* __restrict__ A,
                                               const unsigned short* __restrict__ B,
                                               const float* __restrict__ bias,
                                               float* __restrict__ C,
                                               int M, int N, int K) {
    __shared__ __attribute__((aligned(16))) unsigned short As[2][128 * 32];
    __shared__ __attribute__((aligned(16))) unsigned short Bs[2][128 * 32];
    const int tid = threadIdx.x;
    const int w = tid >> 6, lane = tid & 63;
    const int a = lane & 15, g = lane >> 4;

    const int cpx = gridDim.x >> 3;
    const int nf = ((int)blockIdx.x & 7) * cpx + ((int)blockIdx.x >> 3);
    const int bx = nf >> 5;
    const int by = nf & 31;
    const int m0 = by * 128, n0 = bx * 128;
    const int wr = (w >> 1) * 64, wc = (w & 1) * 64;

    f32x4 acc[4][4];
#pragma unroll
    for (int i = 0; i < 4; i++)
#pragma unroll
        for (int j = 0; j < 4; j++) acc[i][j] = (f32x4)(0.0f);

    const int r0 = tid >> 2;
    const int c0 = (tid & 3) * 8;
    const unsigned short* gA0 = A + (size_t)(m0 + r0) * K + c0;
    const unsigned short* gA1 = A + (size_t)(m0 + 64 + r0) * K + c0;
    const unsigned short* gB0 = B + (size_t)(n0 + r0) * K + c0;
    const unsigned short* gB1 = B + (size_t)(n0 + 64 + r0) * K + c0;

#define GSTAGE(buf_, k0_)                                               \
    {                                                                   \
        char* la_ = (char*)&As[buf_][0] + w * 1024;                     \
        char* lb_ = (char*)&Bs[buf_][0] + w * 1024;                     \
        GLD16(gA0 + (k0_), la_);                                        \
        GLD16(gA1 + (k0_), la_ + 4096);                                 \
        GLD16(gB0 + (k0_), lb_);                                        \
        GLD16(gB1 + (k0_), lb_ + 4096);                                 \
    }

    GSTAGE(0, 0);
    __syncthreads();

    int cur = 0;
    for (int k0 = 0; k0 < K; k0 += 32) {
        if (k0 + 32 < K) GSTAGE(cur ^ 1, k0 + 32);

        bf16x8 af[4], bfr[4];
#pragma unroll
        for (int i = 0; i < 4; i++) {
            af[i]  = *(const bf16x8*)&As[cur][(wr + i * 16 + a) * 32 + g * 8];
            bfr[i] = *(const bf16x8*)&Bs[cur][(wc + i * 16 + a) * 32 + g * 8];
        }
#pragma unroll
        for (int i = 0; i < 4; i++)
#pragma unroll
            for (int j = 0; j < 4; j++) acc[i][j] = mfma_bf16(af[i], bfr[j], acc[i][j]);

        __syncthreads();
        cur ^= 1;
    }
#undef GSTAGE

#pragma unroll
    for (int j = 0; j < 4; j++) {
        const int col = n0 + wc + j * 16 + a;
        const float bv = bias[col];
#pragma unroll
        for (int i = 0; i < 4; i++)
#pragma unroll
            for (int jr = 0; jr < 4; jr++) {
                const int row = m0 + wr + i * 16 + g * 4 + jr;
                C[(size_t)row * N + col] = acc[i][j][jr] + bv;
            }
    }
}

// ===========================================================================
// Causal flash attention (validated): KVBLK=128, swapped QK^T + in-register
// softmax (exp2 domain), XOR-swizzled double-buffered LDS, setprio clusters.
// ===========================================================================

#define STAGE(bf_, t_)                                                  \
    {                                                                   \
        const size_t ko_ = (size_t)(t_) * 128 * LDQ;                    \
        const size_t vo_ = (size_t)(t_) * 128;                          \
        char* db_ = (char*)&KV[bf_][0] + w * 1024;                      \
        GLD16(sK0 + ko_, db_);                                          \
        GLD16(sK1 + ko_, db_ + 8192);                                   \
        GLD16(sV0 + vo_, db_ + 16384);                                  \
        GLD16(sV1 + vo_, db_ + 24576);                                  \
    }

__global__ void __launch_bounds__(512, 4) attn_fwd(const unsigned short* __restrict__ qk,
                                                   const unsigned short* __restrict__ vT,
                                                   unsigned short* __restrict__ o) {
    constexpr int SL = 2048, DH = 64, LDQ = 2048;
    constexpr float GAMMA = 0.18033688011112042f;  // 0.125 * log2(e)
    const int bh = blockIdx.x & 31;
    const int s = blockIdx.x >> 5;
    const int qb = (s < 8) ? 15 - s : s - 8;
    const int b = bh >> 4, h = bh & 15;
    const int tid = threadIdx.x;
    const int w = tid >> 6, lane = tid & 63;
    const int n = lane & 15, g = lane >> 4;

    __shared__ __attribute__((aligned(16))) unsigned short KV[2][16384];

    const int qs = qb * 128 + w * 16 + n;
    const int nt = qb + 1;

    bf16x8 qf[2];
    {
        const unsigned short* qp = qk + (size_t)(b * SL + qs) * LDQ + h * DH + g * 8;
        short8 la = *(const short8*)qp, lb = *(const short8*)(qp + 32);
        short8 s0, s1;
#pragma unroll
        for (int e = 0; e < 8; e++) {
            s0[e] = (short)f2bf(bf2f((unsigned short)la[e]) * GAMMA);
            s1[e] = (short)f2bf(bf2f((unsigned short)lb[e]) * GAMMA);
        }
        qf[0] = __builtin_bit_cast(bf16x8, s0);
        qf[1] = __builtin_bit_cast(bf16x8, s1);
    }

    const int rK = tid >> 3;
    const int xrK = (rK & 3) | (((rK >> 3) & 1) << 2);
    const int csK = (((tid & 7) ^ xrK) << 3);
    const unsigned short* sK0 = qk + (size_t)(b * SL + rK) * LDQ + 1024 + h * DH + csK;
    const unsigned short* sK1 = sK0 + (size_t)64 * LDQ;
    const int dV = tid >> 4;
    const int csV = (((tid & 15) ^ (dV & 7)) << 3);
    const unsigned short* sV0 = vT + (size_t)bh * DH * SL + (size_t)dV * SL + csV;
    const unsigned short* sV1 = sV0 + (size_t)32 * SL;

    const int srow = 8 * (n >> 2) + (n & 3);
    const int xrq = (n & 3) | (((n >> 2) & 1) << 2);
    const int offK0 = ((g ^ xrq) << 3);
    const int offK1 = offK0 ^ 32;
    int offV[4];
#pragma unroll
    for (int kc = 0; kc < 4; kc++) offV[kc] = (((4 * kc + g) ^ (n & 7)) << 3);

    f32x4 of[4];
#pragma unroll
    for (int i = 0; i < 4; i++) of[i] = (f32x4)(0.0f);
    float m_i = -1e30f, l_i = 0.0f;

    STAGE(0, 0);
    __syncthreads();

    for (int t = 0; t < nt; ++t) {
        const unsigned short* kvb = &KV[t & 1][0];
        if (t + 1 < nt) STAGE((t & 1) ^ 1, t + 1);

        f32x4 p[8];
        __builtin_amdgcn_s_setprio(1);
#pragma unroll
        for (int f = 0; f < 8; f++) {
            const int r_ = srow + ((f >> 1) << 5) + ((f & 1) << 2);
            const bf16x8 ka_ = *(const bf16x8*)&kvb[r_ * 64 + offK0];
            const bf16x8 kc_ = *(const bf16x8*)&kvb[r_ * 64 + offK1];
            f32x4 acc_ = (f32x4)(0.0f);
            acc_ = mfma_bf16(ka_, qf[0], acc_);
            acc_ = mfma_bf16(kc_, qf[1], acc_);
            p[f] = acc_;
        }
        __builtin_amdgcn_s_setprio(0);

        if (t == nt - 1) {
            const int k0 = t * 128;
#pragma unroll
            for (int f = 0; f < 8; f++) {
                const int kb_ = k0 + ((f >> 1) << 5) + ((f & 1) << 2) + 8 * g;
#pragma unroll
                for (int e = 0; e < 4; e++)
                    if (kb_ + e > qs) p[f][e] = -1e30f;
            }
        }

        float mx = -1e30f;
#pragma unroll
        for (int f = 0; f < 8; f++) {
            const float a_ = fmaxf(fmaxf(p[f][0], p[f][1]), fmaxf(p[f][2], p[f][3]));
            mx = fmaxf(mx, a_);
        }
        mx = fmaxf(mx, __shfl_xor(mx, 16));
        mx = fmaxf(mx, __shfl_xor(mx, 32));
        if (!__all(mx <= m_i + 8.0f)) {
            const float mn_ = fmaxf(m_i, mx);
            const float al_ = __builtin_amdgcn_exp2f(m_i - mn_);
            l_i *= al_;
#pragma unroll
            for (int d_ = 0; d_ < 4; d_++) of[d_] = of[d_] * al_;
            m_i = mn_;
        }
        float rs = 0.0f;
#pragma unroll
        for (int f = 0; f < 8; f++)
#pragma unroll
            for (int e = 0; e < 4; e++) {
                p[f][e] = __builtin_amdgcn_exp2f(p[f][e] - m_i);
                rs += p[f][e];
            }
        l_i += rs;

        bf16x8 pf[4];
#pragma unroll
        for (int kc = 0; kc < 4; kc++) {
            uint4v u_;
            u_[0] = pkbf(p[2 * kc][0], p[2 * kc][1]);
            u_[1] = pkbf(p[2 * kc][2], p[2 * kc][3]);
            u_[2] = pkbf(p[2 * kc + 1][0], p[2 * kc + 1][1]);
            u_[3] = pkbf(p[2 * kc + 1][2], p[2 * kc + 1][3]);
            pf[kc] = __builtin_bit_cast(bf16x8, u_);
        }

        const unsigned short* vb = kvb + 8192;
        __builtin_amdgcn_s_setprio(1);
#pragma unroll
        for (int df = 0; df < 4; df++) {
            const int vrow = (df * 16 + n) * 128;
#pragma unroll
            for (int kc = 0; kc < 4; kc++) {
                const bf16x8 va_ = *(const bf16x8*)&vb[vrow + offV[kc]];
                of[df] = mfma_bf16(va_, pf[kc], of[df]);
            }
        }
        __builtin_amdgcn_s_setprio(0);

        __syncthreads();
    }

    float rl = l_i;
    rl += __shfl_xor(rl, 16);
    rl += __shfl_xor(rl, 32);
    const float inv = 1.0f / rl;
    unsigned short* op = o + (size_t)(b * SL + qs) * 1024 + h * DH + 4 * g;
#pragma unroll
    for (int df = 0; df < 4; df++) {
        ushort4v st;
#pragma unroll
        for (int r = 0; r < 4; r++) st[r] = f2bf(of[df][r] * inv);
        *(ushort4v*)(op + df * 16) = st;
    }
}

// ---------------------------------------------------------------------------
extern "C" void kernel_launch(void* const* d_in, const int* in_sizes, int n_in,
                              void* d_out, int out_size, void* d_ws, size_t ws_size,
                              hipStream_t stream) {
    (void)in_sizes; (void)n_in; (void)out_size; (void)ws_size;
    const float* x    = (const float*)d_in[0];
    const float* Wqkv = (const float*)d_in[1];
    const float* bqkv = (const float*)d_in[2];
    const float* Wout = (const float*)d_in[3];
    const float* bout = (const float*)d_in[4];
    float* out = (float*)d_out;

    const int BS = 2, SL = 2048, DM = 1024;
    const int M = BS * SL;   // 4096
    const int K = DM;        // 1024

    // ws layout: x_bf 8M | wqkv_bf 6M | wout_bf 2M | qk 16M | vT 8M | attn_o 8M = 48M
    char* ws = (char*)d_ws;
    unsigned short* x_bf    = (unsigned short*)(ws);
    unsigned short* wqkv_bf = (unsigned short*)(ws + (8u << 20));
    unsigned short* wout_bf = (unsigned short*)(ws + (14u << 20));
    unsigned short* qkbuf   = (unsigned short*)(ws + (16u << 20));
    unsigned short* vTbuf   = (unsigned short*)(ws + (32u << 20));
    unsigned short* attn_o  = (unsigned short*)(ws + (40u << 20));

    cvt_all<<<2048, 256, 0, stream>>>(x, Wqkv, Wout, x_bf, wqkv_bf, wout_bf);

    gemm_qkv<<<dim3(256), 512, 0, stream>>>(x_bf, wqkv_bf, bqkv, qkbuf, vTbuf);

    attn_fwd<<<dim3(512), 512, 0, stream>>>(qkbuf, vTbuf, attn_o);

    gemm_bt<<<dim3(256), 256, 0, stream>>>(attn_o, wout_bf, bout, out, M, DM, K);
}

// Round 18
// 102.885 us; speedup vs baseline: 1.0032x; 1.0032x over previous
//
#include <hip/hip_runtime.h>
#include <cstdint>

typedef __attribute__((ext_vector_type(8))) __bf16 bf16x8;
typedef __attribute__((ext_vector_type(4))) float f32x4;
typedef __attribute__((ext_vector_type(8))) short short8;
typedef __attribute__((ext_vector_type(4))) float float4v;
typedef __attribute__((ext_vector_type(4))) unsigned uint4v;
typedef __attribute__((ext_vector_type(4))) unsigned short ushort4v;

__device__ __forceinline__ unsigned short f2bf(float f) {
    unsigned u = __builtin_bit_cast(unsigned, f);
    u += 0x7fffu + ((u >> 16) & 1u);   // RNE
    return (unsigned short)(u >> 16);
}
__device__ __forceinline__ float bf2f(unsigned short s) {
    return __builtin_bit_cast(float, (unsigned)s << 16);
}
__device__ __forceinline__ f32x4 mfma_bf16(bf16x8 a, bf16x8 b, f32x4 c) {
    return __builtin_amdgcn_mfma_f32_16x16x32_bf16(a, b, c, 0, 0, 0);
}
// pack 2 f32 -> 2 bf16 in one u32 (lo = first arg), RNE
__device__ __forceinline__ unsigned pkbf(float lo, float hi) {
    unsigned r;
    asm("v_cvt_pk_bf16_f32 %0, %1, %2" : "=v"(r) : "v"(lo), "v"(hi));
    return r;
}

#define GLD16(g, l)                                                                     \
    __builtin_amdgcn_global_load_lds((const __attribute__((address_space(1))) void*)(g), \
                                     (__attribute__((address_space(3))) void*)(l), 16, 0, 0)

// ---------------------------------------------------------------------------
// fp32 -> bf16 for ALL THREE arrays in one launch (x | Wqkv | Wout).
// ---------------------------------------------------------------------------
__global__ void __launch_bounds__(256) cvt_all(const float* __restrict__ x,
                                               const float* __restrict__ wqkv,
                                               const float* __restrict__ wout,
                                               unsigned short* __restrict__ xb,
                                               unsigned short* __restrict__ wqb,
                                               unsigned short* __restrict__ wob) {
    int i = blockIdx.x * blockDim.x + threadIdx.x;
#pragma unroll
    for (int k = 0; k < 2; k++, i += 524288) {
        const float* s;
        unsigned short* d;
        int off;
        if (i < 524288)      { s = x;    d = xb;  off = i; }
        else if (i < 917504) { s = wqkv; d = wqb; off = i - 524288; }
        else                 { s = wout; d = wob; off = i - 917504; }
        const float4v* sp = (const float4v*)(s + (size_t)off * 8);
        float4v v0 = sp[0], v1 = sp[1];
        uint4v u;
        u[0] = pkbf(v0[0], v0[1]);
        u[1] = pkbf(v0[2], v0[3]);
        u[2] = pkbf(v1[0], v1[1]);
        u[3] = pkbf(v1[2], v1[3]);
        *(uint4v*)(d + (size_t)off * 8) = u;
    }
}

// ===========================================================================
// GEMM1 (QKV) v18: R17's schedule with the 4 POST-MFMA barriers removed
// (9 -> 5 barriers per K-tile).  Within a tile, stores target buffer nx and
// reads target buffer c — no conflict, so the post-MFMA barriers were pure
// scheduling overhead.  A wave finishing MFMA(p) immediately issues
// reads(p+1) + stores, overlapping other waves' MFMA; the pre-MFMA barrier
// re-syncs.  vmcnt discipline unchanged from R17:
//   tile top: vmcnt(2)+barrier (early-5 landed; late-2 A1/A3 keep flying)
//   phase 2:  vmcnt(5) before its barrier (retires late-2 of current tile
//             before phase-3/4 reads of A1/A3 regions); last tile vmcnt(0).
// ===========================================================================

#define STG_A(bf_, i_, t_) \
    GLD16(gA + (size_t)(i_) * 64 * 1024 + (size_t)(t_) * 64, (char*)&Asl[bf_][0] + (i_) * 8192 + w * 1024)
#define STG_B(bf_, i_, t_) \
    GLD16(gB + (size_t)(i_) * 64 * 1024 + (size_t)(t_) * 64, (char*)&Bsl[bf_][0] + (i_) * 8192 + w * 1024)

#define LDA(c_, mf_, kk_) \
    (*(const bf16x8*)((const char*)&Asl[c_][0] + (wm * 128 + (mf_) * 16 + a) * 128 + (((((kk_) << 2) + g) ^ xa) << 4)))
#define LDB(c_, nf_, kk_) \
    (*(const bf16x8*)((const char*)&Bsl[c_][0] + (wn * 48 + (nf_) * 16 + a) * 128 + (((((kk_) << 2) + g) ^ xa) << 4)))

#define MFMA12(mb_)                                                               \
    __builtin_amdgcn_s_setprio(1);                                                \
    _Pragma("unroll") for (int nf_ = 0; nf_ < 3; nf_++) {                         \
        acc[mb_][nf_]       = mfma_bf16(a0_, bfr[nf_][0], acc[mb_][nf_]);         \
        acc[mb_][nf_]       = mfma_bf16(a1_, bfr[nf_][1], acc[mb_][nf_]);         \
        acc[(mb_) + 1][nf_] = mfma_bf16(a2_, bfr[nf_][0], acc[(mb_) + 1][nf_]);   \
        acc[(mb_) + 1][nf_] = mfma_bf16(a3_, bfr[nf_][1], acc[(mb_) + 1][nf_]);   \
    }                                                                             \
    __builtin_amdgcn_s_setprio(0);

__global__ void __launch_bounds__(512, 2) gemm_qkv(const unsigned short* __restrict__ A,
                                                   const unsigned short* __restrict__ B,
                                                   const float* __restrict__ bias,
                                                   unsigned short* __restrict__ qkbuf,
                                                   unsigned short* __restrict__ vT) {
    constexpr int K = 1024;
    __shared__ __attribute__((aligned(16))) unsigned short Asl[2][256 * 64];  // 2x32KB
    __shared__ __attribute__((aligned(16))) unsigned short Bsl[2][192 * 64];  // 2x24KB
    const int tid = threadIdx.x;
    const int w = tid >> 6, lane = tid & 63;
    const int a = lane & 15, g = lane >> 4;
    const int xa = a & 7;
    const int wm = w >> 2, wn = w & 3;

    // XCD swizzle (256 blocks, bijective): 32 consecutive per XCD
    const int nfb = ((int)blockIdx.x & 7) * 32 + ((int)blockIdx.x >> 3);
    const int bx = nfb >> 4, by = nfb & 15;
    const int m0 = by * 256, n0 = bx * 192;

    f32x4 acc[8][3];
#pragma unroll
    for (int i = 0; i < 8; i++)
#pragma unroll
        for (int j = 0; j < 3; j++) acc[i][j] = (f32x4)(0.0f);

    const int rA = tid >> 3, uA = tid & 7;
    const unsigned short* gA = A + (size_t)(m0 + rA) * K + ((uA ^ (rA & 7)) << 3);
    const unsigned short* gB = B + (size_t)(n0 + rA) * K + ((uA ^ (rA & 7)) << 3);

    // prologue: stage tile 0, EARLY (B0,B1,B2,A0,A2) then LATE (A1,A3)
    STG_B(0, 0, 0); STG_B(0, 1, 0); STG_B(0, 2, 0);
    STG_A(0, 0, 0); STG_A(0, 2, 0);
    STG_A(0, 1, 0); STG_A(0, 3, 0);

    for (int t = 0; t < 16; ++t) {
        const int c = t & 1, nx = c ^ 1;
        const bool more = (t < 15);

        // tile top: early-5 of current tile landed; late-2 still flying.
        asm volatile("s_waitcnt vmcnt(2)" ::: "memory");
        __builtin_amdgcn_s_barrier();

        bf16x8 bfr[3][2];
#pragma unroll
        for (int nf = 0; nf < 3; nf++) {
            bfr[nf][0] = LDB(c, nf, 0);
            bfr[nf][1] = LDB(c, nf, 1);
        }

        {   // phase 1: reads rows 0-31 of wave-half (early regions)
            bf16x8 a0_ = LDA(c, 0, 0), a1_ = LDA(c, 0, 1);
            bf16x8 a2_ = LDA(c, 1, 0), a3_ = LDA(c, 1, 1);
            if (more) { STG_B(nx, 0, t + 1); STG_B(nx, 1, t + 1); STG_B(nx, 2, t + 1); }
            asm volatile("" ::: "memory");
            __builtin_amdgcn_s_barrier();
            asm volatile("s_waitcnt lgkmcnt(0)");
            MFMA12(0);
        }
        {   // phase 2: rows 32-63 (early); retire late-2 before its barrier
            bf16x8 a0_ = LDA(c, 2, 0), a1_ = LDA(c, 2, 1);
            bf16x8 a2_ = LDA(c, 3, 0), a3_ = LDA(c, 3, 1);
            if (more) { STG_A(nx, 0, t + 1); STG_A(nx, 2, t + 1); }
            asm volatile("" ::: "memory");
            if (more) asm volatile("s_waitcnt vmcnt(5)" ::: "memory");
            else      asm volatile("s_waitcnt vmcnt(0)" ::: "memory");
            __builtin_amdgcn_s_barrier();
            asm volatile("s_waitcnt lgkmcnt(0)");
            MFMA12(2);
        }
        {   // phase 3: rows 64-95 (A1/A3 — complete after phase-2 barrier)
            bf16x8 a0_ = LDA(c, 4, 0), a1_ = LDA(c, 4, 1);
            bf16x8 a2_ = LDA(c, 5, 0), a3_ = LDA(c, 5, 1);
            if (more) { STG_A(nx, 1, t + 1); }
            asm volatile("" ::: "memory");
            __builtin_amdgcn_s_barrier();
            asm volatile("s_waitcnt lgkmcnt(0)");
            MFMA12(4);
        }
        {   // phase 4: rows 96-127
            bf16x8 a0_ = LDA(c, 6, 0), a1_ = LDA(c, 6, 1);
            bf16x8 a2_ = LDA(c, 7, 0), a3_ = LDA(c, 7, 1);
            if (more) { STG_A(nx, 3, t + 1); }
            asm volatile("" ::: "memory");
            __builtin_amdgcn_s_barrier();
            asm volatile("s_waitcnt lgkmcnt(0)");
            MFMA12(6);
        }
        // no post-MFMA barrier: next tile-top barrier provides the
        // read(c) / store(c-as-nx) separation.
    }

    // ---- epilogue (verified R15-R17) ----
#pragma unroll
    for (int nf = 0; nf < 3; nf++) {
        const int cb = n0 + wn * 48 + nf * 16;
        const int col = cb + a;
        const float bv = bias[col];
        if (cb < 2048) {   // Q/K -> qk buffer (ldc = 2048)
#pragma unroll
            for (int mf = 0; mf < 8; mf++)
#pragma unroll
                for (int jr = 0; jr < 4; jr++) {
                    const int row = m0 + wm * 128 + mf * 16 + g * 4 + jr;
                    qkbuf[(size_t)row * 2048 + col] = f2bf(acc[mf][nf][jr] + bv);
                }
        } else {           // V -> vT[(b*16+h)][d][token], 4-token packs
            const int vd = col - 2048, hh = vd >> 6, dd = vd & 63;
#pragma unroll
            for (int mf = 0; mf < 8; mf++) {
                const int t0 = m0 + wm * 128 + mf * 16 + g * 4;
                const int bb = t0 >> 11, kl = t0 & 2047;
                ushort4v st;
#pragma unroll
                for (int jr = 0; jr < 4; jr++) st[jr] = f2bf(acc[mf][nf][jr] + bv);
                *(ushort4v*)(vT + ((size_t)((bb << 4) + hh) * 64 + dd) * 2048 + kl) = st;
            }
        }
    }
}

// ---------------------------------------------------------------------------
// GEMM2: C[M,N] = A[M,K]*B[N,K]^T + bias[N].  128x128 tile, BK=32, 4 waves.
// 2-PHASE double-buffered LDS (known-good structure; grid 256 = exact fill).
// ---------------------------------------------------------------------------
__global__ void __launch_bounds__(256) gemm_bt(const unsigned short* __restrict__ A,
                                               const unsigned short* __restrict__ B,
                                               const float* __restrict__ bias,
                                               float* __restrict__ C,
                                               int M, int N, int K) {
    __shared__ __attribute__((aligned(16))) unsigned short As[2][128 * 32];
    __shared__ __attribute__((aligned(16))) unsigned short Bs[2][128 * 32];
    const int tid = threadIdx.x;
    const int w = tid >> 6, lane = tid & 63;
    const int a = lane & 15, g = lane >> 4;

    const int cpx = gridDim.x >> 3;
    const int nf = ((int)blockIdx.x & 7) * cpx + ((int)blockIdx.x >> 3);
    const int bx = nf >> 5;
    const int by = nf & 31;
    const int m0 = by * 128, n0 = bx * 128;
    const int wr = (w >> 1) * 64, wc = (w & 1) * 64;

    f32x4 acc[4][4];
#pragma unroll
    for (int i = 0; i < 4; i++)
#pragma unroll
        for (int j = 0; j < 4; j++) acc[i][j] = (f32x4)(0.0f);

    const int r0 = tid >> 2;
    const int c0 = (tid & 3) * 8;
    const unsigned short* gA0 = A + (size_t)(m0 + r0) * K + c0;
    const unsigned short* gA1 = A + (size_t)(m0 + 64 + r0) * K + c0;
    const unsigned short* gB0 = B + (size_t)(n0 + r0) * K + c0;
    const unsigned short* gB1 = B + (size_t)(n0 + 64 + r0) * K + c0;

#define GSTAGE(buf_, k0_)                                               \
    {                                                                   \
        char* la_ = (char*)&As[buf_][0] + w * 1024;                     \
        char* lb_ = (char*)&Bs[buf_][0] + w * 1024;                     \
        GLD16(gA0 + (k0_), la_);                                        \
        GLD16(gA1 + (k0_), la_ + 4096);                                 \
        GLD16(gB0 + (k0_), lb_);                                        \
        GLD16(gB1 + (k0_), lb_ + 4096);                                 \
    }

    GSTAGE(0, 0);
    __syncthreads();

    int cur = 0;
    for (int k0 = 0; k0 < K; k0 += 32) {
        if (k0 + 32 < K) GSTAGE(cur ^ 1, k0 + 32);

        bf16x8 af[4], bfr[4];
#pragma unroll
        for (int i = 0; i < 4; i++) {
            af[i]  = *(const bf16x8*)&As[cur][(wr + i * 16 + a) * 32 + g * 8];
            bfr[i] = *(const bf16x8*)&Bs[cur][(wc + i * 16 + a) * 32 + g * 8];
        }
#pragma unroll
        for (int i = 0; i < 4; i++)
#pragma unroll
            for (int j = 0; j < 4; j++) acc[i][j] = mfma_bf16(af[i], bfr[j], acc[i][j]);

        __syncthreads();
        cur ^= 1;
    }
#undef GSTAGE

#pragma unroll
    for (int j = 0; j < 4; j++) {
        const int col = n0 + wc + j * 16 + a;
        const float bv = bias[col];
#pragma unroll
        for (int i = 0; i < 4; i++)
#pragma unroll
            for (int jr = 0; jr < 4; jr++) {
                const int row = m0 + wr + i * 16 + g * 4 + jr;
                C[(size_t)row * N + col] = acc[i][j][jr] + bv;
            }
    }
}

// ===========================================================================
// Causal flash attention (validated): KVBLK=128, swapped QK^T + in-register
// softmax (exp2 domain), XOR-swizzled double-buffered LDS, setprio clusters.
// ===========================================================================

#define STAGE(bf_, t_)                                                  \
    {                                                                   \
        const size_t ko_ = (size_t)(t_) * 128 * LDQ;                    \
        const size_t vo_ = (size_t)(t_) * 128;                          \
        char* db_ = (char*)&KV[bf_][0] + w * 1024;                      \
        GLD16(sK0 + ko_, db_);                                          \
        GLD16(sK1 + ko_, db_ + 8192);                                   \
        GLD16(sV0 + vo_, db_ + 16384);                                  \
        GLD16(sV1 + vo_, db_ + 24576);                                  \
    }

__global__ void __launch_bounds__(512, 4) attn_fwd(const unsigned short* __restrict__ qk,
                                                   const unsigned short* __restrict__ vT,
                                                   unsigned short* __restrict__ o) {
    constexpr int SL = 2048, DH = 64, LDQ = 2048;
    constexpr float GAMMA = 0.18033688011112042f;  // 0.125 * log2(e)
    const int bh = blockIdx.x & 31;
    const int s = blockIdx.x >> 5;
    const int qb = (s < 8) ? 15 - s : s - 8;
    const int b = bh >> 4, h = bh & 15;
    const int tid = threadIdx.x;
    const int w = tid >> 6, lane = tid & 63;
    const int n = lane & 15, g = lane >> 4;

    __shared__ __attribute__((aligned(16))) unsigned short KV[2][16384];

    const int qs = qb * 128 + w * 16 + n;
    const int nt = qb + 1;

    bf16x8 qf[2];
    {
        const unsigned short* qp = qk + (size_t)(b * SL + qs) * LDQ + h * DH + g * 8;
        short8 la = *(const short8*)qp, lb = *(const short8*)(qp + 32);
        short8 s0, s1;
#pragma unroll
        for (int e = 0; e < 8; e++) {
            s0[e] = (short)f2bf(bf2f((unsigned short)la[e]) * GAMMA);
            s1[e] = (short)f2bf(bf2f((unsigned short)lb[e]) * GAMMA);
        }
        qf[0] = __builtin_bit_cast(bf16x8, s0);
        qf[1] = __builtin_bit_cast(bf16x8, s1);
    }

    const int rK = tid >> 3;
    const int xrK = (rK & 3) | (((rK >> 3) & 1) << 2);
    const int csK = (((tid & 7) ^ xrK) << 3);
    const unsigned short* sK0 = qk + (size_t)(b * SL + rK) * LDQ + 1024 + h * DH + csK;
    const unsigned short* sK1 = sK0 + (size_t)64 * LDQ;
    const int dV = tid >> 4;
    const int csV = (((tid & 15) ^ (dV & 7)) << 3);
    const unsigned short* sV0 = vT + (size_t)bh * DH * SL + (size_t)dV * SL + csV;
    const unsigned short* sV1 = sV0 + (size_t)32 * SL;

    const int srow = 8 * (n >> 2) + (n & 3);
    const int xrq = (n & 3) | (((n >> 2) & 1) << 2);
    const int offK0 = ((g ^ xrq) << 3);
    const int offK1 = offK0 ^ 32;
    int offV[4];
#pragma unroll
    for (int kc = 0; kc < 4; kc++) offV[kc] = (((4 * kc + g) ^ (n & 7)) << 3);

    f32x4 of[4];
#pragma unroll
    for (int i = 0; i < 4; i++) of[i] = (f32x4)(0.0f);
    float m_i = -1e30f, l_i = 0.0f;

    STAGE(0, 0);
    __syncthreads();

    for (int t = 0; t < nt; ++t) {
        const unsigned short* kvb = &KV[t & 1][0];
        if (t + 1 < nt) STAGE((t & 1) ^ 1, t + 1);

        f32x4 p[8];
        __builtin_amdgcn_s_setprio(1);
#pragma unroll
        for (int f = 0; f < 8; f++) {
            const int r_ = srow + ((f >> 1) << 5) + ((f & 1) << 2);
            const bf16x8 ka_ = *(const bf16x8*)&kvb[r_ * 64 + offK0];
            const bf16x8 kc_ = *(const bf16x8*)&kvb[r_ * 64 + offK1];
            f32x4 acc_ = (f32x4)(0.0f);
            acc_ = mfma_bf16(ka_, qf[0], acc_);
            acc_ = mfma_bf16(kc_, qf[1], acc_);
            p[f] = acc_;
        }
        __builtin_amdgcn_s_setprio(0);

        if (t == nt - 1) {
            const int k0 = t * 128;
#pragma unroll
            for (int f = 0; f < 8; f++) {
                const int kb_ = k0 + ((f >> 1) << 5) + ((f & 1) << 2) + 8 * g;
#pragma unroll
                for (int e = 0; e < 4; e++)
                    if (kb_ + e > qs) p[f][e] = -1e30f;
            }
        }

        float mx = -1e30f;
#pragma unroll
        for (int f = 0; f < 8; f++) {
            const float a_ = fmaxf(fmaxf(p[f][0], p[f][1]), fmaxf(p[f][2], p[f][3]));
            mx = fmaxf(mx, a_);
        }
        mx = fmaxf(mx, __shfl_xor(mx, 16));
        mx = fmaxf(mx, __shfl_xor(mx, 32));
        if (!__all(mx <= m_i + 8.0f)) {
            const float mn_ = fmaxf(m_i, mx);
            const float al_ = __builtin_amdgcn_exp2f(m_i - mn_);
            l_i *= al_;
#pragma unroll
            for (int d_ = 0; d_ < 4; d_++) of[d_] = of[d_] * al_;
            m_i = mn_;
        }
        float rs = 0.0f;
#pragma unroll
        for (int f = 0; f < 8; f++)
#pragma unroll
            for (int e = 0; e < 4; e++) {
                p[f][e] = __builtin_amdgcn_exp2f(p[f][e] - m_i);
                rs += p[f][e];
            }
        l_i += rs;

        bf16x8 pf[4];
#pragma unroll
        for (int kc = 0; kc < 4; kc++) {
            uint4v u_;
            u_[0] = pkbf(p[2 * kc][0], p[2 * kc][1]);
            u_[1] = pkbf(p[2 * kc][2], p[2 * kc][3]);
            u_[2] = pkbf(p[2 * kc + 1][0], p[2 * kc + 1][1]);
            u_[3] = pkbf(p[2 * kc + 1][2], p[2 * kc + 1][3]);
            pf[kc] = __builtin_bit_cast(bf16x8, u_);
        }

        const unsigned short* vb = kvb + 8192;
        __builtin_amdgcn_s_setprio(1);
#pragma unroll
        for (int df = 0; df < 4; df++) {
            const int vrow = (df * 16 + n) * 128;
#pragma unroll
            for (int kc = 0; kc < 4; kc++) {
                const bf16x8 va_ = *(const bf16x8*)&vb[vrow + offV[kc]];
                of[df] = mfma_bf16(va_, pf[kc], of[df]);
            }
        }
        __builtin_amdgcn_s_setprio(0);

        __syncthreads();
    }

    float rl = l_i;
    rl += __shfl_xor(rl, 16);
    rl += __shfl_xor(rl, 32);
    const float inv = 1.0f / rl;
    unsigned short* op = o + (size_t)(b * SL + qs) * 1024 + h * DH + 4 * g;
#pragma unroll
    for (int df = 0; df < 4; df++) {
        ushort4v st;
#pragma unroll
        for (int r = 0; r < 4; r++) st[r] = f2bf(of[df][r] * inv);
        *(ushort4v*)(op + df * 16) = st;
    }
}

// ---------------------------------------------------------------------------
extern "C" void kernel_launch(void* const* d_in, const int* in_sizes, int n_in,
                              void* d_out, int out_size, void* d_ws, size_t ws_size,
                              hipStream_t stream) {
    (void)in_sizes; (void)n_in; (void)out_size; (void)ws_size;
    const float* x    = (const float*)d_in[0];
    const float* Wqkv = (const float*)d_in[1];
    const float* bqkv = (const float*)d_in[2];
    const float* Wout = (const float*)d_in[3];
    const float* bout = (const float*)d_in[4];
    float* out = (float*)d_out;

    const int BS = 2, SL = 2048, DM = 1024;
    const int M = BS * SL;   // 4096
    const int K = DM;        // 1024

    // ws layout: x_bf 8M | wqkv_bf 6M | wout_bf 2M | qk 16M | vT 8M | attn_o 8M = 48M
    char* ws = (char*)d_ws;
    unsigned short* x_bf    = (unsigned short*)(ws);
    unsigned short* wqkv_bf = (unsigned short*)(ws + (8u << 20));
    unsigned short* wout_bf = (unsigned short*)(ws + (14u << 20));
    unsigned short* qkbuf   = (unsigned short*)(ws + (16u << 20));
    unsigned short* vTbuf   = (unsigned short*)(ws + (32u << 20));
    unsigned short* attn_o  = (unsigned short*)(ws + (40u << 20));

    cvt_all<<<2048, 256, 0, stream>>>(x, Wqkv, Wout, x_bf, wqkv_bf, wout_bf);

    gemm_qkv<<<dim3(256), 512, 0, stream>>>(x_bf, wqkv_bf, bqkv, qkbuf, vTbuf);

    attn_fwd<<<dim3(512), 512, 0, stream>>>(qkbuf, vTbuf, attn_o);

    gemm_bt<<<dim3(256), 256, 0, stream>>>(attn_o, wout_bf, bout, out, M, DM, K);
}

// Round 19
// 99.471 us; speedup vs baseline: 1.0377x; 1.0343x over previous
//
#include <hip/hip_runtime.h>
#include <cstdint>

typedef __attribute__((ext_vector_type(8))) __bf16 bf16x8;
typedef __attribute__((ext_vector_type(4))) float f32x4;
typedef __attribute__((ext_vector_type(8))) short short8;
typedef __attribute__((ext_vector_type(4))) float float4v;
typedef __attribute__((ext_vector_type(4))) unsigned uint4v;
typedef __attribute__((ext_vector_type(4))) unsigned short ushort4v;

__device__ __forceinline__ unsigned short f2bf(float f) {
    unsigned u = __builtin_bit_cast(unsigned, f);
    u += 0x7fffu + ((u >> 16) & 1u);   // RNE
    return (unsigned short)(u >> 16);
}
__device__ __forceinline__ float bf2f(unsigned short s) {
    return __builtin_bit_cast(float, (unsigned)s << 16);
}
__device__ __forceinline__ f32x4 mfma_bf16(bf16x8 a, bf16x8 b, f32x4 c) {
    return __builtin_amdgcn_mfma_f32_16x16x32_bf16(a, b, c, 0, 0, 0);
}
// pack 2 f32 -> 2 bf16 in one u32 (lo = first arg), RNE
__device__ __forceinline__ unsigned pkbf(float lo, float hi) {
    unsigned r;
    asm("v_cvt_pk_bf16_f32 %0, %1, %2" : "=v"(r) : "v"(lo), "v"(hi));
    return r;
}

#define GLD16(g, l)                                                                     \
    __builtin_amdgcn_global_load_lds((const __attribute__((address_space(1))) void*)(g), \
                                     (__attribute__((address_space(3))) void*)(l), 16, 0, 0)

// ---------------------------------------------------------------------------
// fp32 -> bf16 for ALL THREE arrays in one launch (x | Wqkv | Wout).
// ---------------------------------------------------------------------------
__global__ void __launch_bounds__(256) cvt_all(const float* __restrict__ x,
                                               const float* __restrict__ wqkv,
                                               const float* __restrict__ wout,
                                               unsigned short* __restrict__ xb,
                                               unsigned short* __restrict__ wqb,
                                               unsigned short* __restrict__ wob) {
    int i = blockIdx.x * blockDim.x + threadIdx.x;
#pragma unroll
    for (int k = 0; k < 2; k++, i += 524288) {
        const float* s;
        unsigned short* d;
        int off;
        if (i < 524288)      { s = x;    d = xb;  off = i; }
        else if (i < 917504) { s = wqkv; d = wqb; off = i - 524288; }
        else                 { s = wout; d = wob; off = i - 917504; }
        const float4v* sp = (const float4v*)(s + (size_t)off * 8);
        float4v v0 = sp[0], v1 = sp[1];
        uint4v u;
        u[0] = pkbf(v0[0], v0[1]);
        u[1] = pkbf(v0[2], v0[3]);
        u[2] = pkbf(v1[0], v1[1]);
        u[3] = pkbf(v1[2], v1[3]);
        *(uint4v*)(d + (size_t)off * 8) = u;
    }
}

// ===========================================================================
// GEMM1 (QKV) v19: phased schedule x CO-RESIDENCY.
// Tile 128x192, BK=64, 8 waves (2Mx4N; per-wave 64x48), LDS = A 2x16KB +
// B 2x24KB = 80KB -> EXACTLY 2 blocks/CU; grid 32x16 = 512 = exact 2/CU
// fill.  R16's proven two-barrier phase discipline, 2 phases/tile of 12
// MFMA; tile-top vmcnt(0)+barrier (loads a full tile old; R17 showed
// counted-vmcnt is not the lever).  The co-resident sibling block hides
// tile-top drain + barrier skew that the schedule cannot touch at 1/CU.
// Swizzle: element (r,c) at byte r*128 + (((c>>3)^(r&7))<<4)+(c&7)*2;
// GLD16 dest linear, source carries the inverse (verified R15-R18).
// ===========================================================================

#define STG_A(bf_, i_, t_) \
    GLD16(gA + (size_t)(i_) * 64 * 1024 + (size_t)(t_) * 64, (char*)&Asl[bf_][0] + (i_) * 8192 + w * 1024)
#define STG_B(bf_, i_, t_) \
    GLD16(gB + (size_t)(i_) * 64 * 1024 + (size_t)(t_) * 64, (char*)&Bsl[bf_][0] + (i_) * 8192 + w * 1024)

#define LDA(c_, mf_, kk_) \
    (*(const bf16x8*)((const char*)&Asl[c_][0] + (wm * 64 + (mf_) * 16 + a) * 128 + (((((kk_) << 2) + g) ^ xa) << 4)))
#define LDB(c_, nf_, kk_) \
    (*(const bf16x8*)((const char*)&Bsl[c_][0] + (wn * 48 + (nf_) * 16 + a) * 128 + (((((kk_) << 2) + g) ^ xa) << 4)))

#define MFMA12(mb_)                                                               \
    __builtin_amdgcn_s_setprio(1);                                                \
    _Pragma("unroll") for (int nf_ = 0; nf_ < 3; nf_++) {                         \
        acc[mb_][nf_]       = mfma_bf16(a0_, bfr[nf_][0], acc[mb_][nf_]);         \
        acc[mb_][nf_]       = mfma_bf16(a1_, bfr[nf_][1], acc[mb_][nf_]);         \
        acc[(mb_) + 1][nf_] = mfma_bf16(a2_, bfr[nf_][0], acc[(mb_) + 1][nf_]);   \
        acc[(mb_) + 1][nf_] = mfma_bf16(a3_, bfr[nf_][1], acc[(mb_) + 1][nf_]);   \
    }                                                                             \
    __builtin_amdgcn_s_setprio(0);

__global__ void __launch_bounds__(512, 4) gemm_qkv(const unsigned short* __restrict__ A,
                                                   const unsigned short* __restrict__ B,
                                                   const float* __restrict__ bias,
                                                   unsigned short* __restrict__ qkbuf,
                                                   unsigned short* __restrict__ vT) {
    constexpr int K = 1024;
    __shared__ __attribute__((aligned(16))) unsigned short Asl[2][128 * 64];  // 2x16KB
    __shared__ __attribute__((aligned(16))) unsigned short Bsl[2][192 * 64];  // 2x24KB
    const int tid = threadIdx.x;
    const int w = tid >> 6, lane = tid & 63;
    const int a = lane & 15, g = lane >> 4;
    const int xa = a & 7;
    const int wm = w >> 2, wn = w & 3;

    // XCD swizzle (512 blocks, bijective): 64 consecutive per XCD
    const int nfb = ((int)blockIdx.x & 7) * 64 + ((int)blockIdx.x >> 3);
    const int bx = nfb >> 5, by = nfb & 31;
    const int m0 = by * 128, n0 = bx * 192;

    f32x4 acc[4][3];
#pragma unroll
    for (int i = 0; i < 4; i++)
#pragma unroll
        for (int j = 0; j < 3; j++) acc[i][j] = (f32x4)(0.0f);

    const int rA = tid >> 3, uA = tid & 7;
    const unsigned short* gA = A + (size_t)(m0 + rA) * K + ((uA ^ (rA & 7)) << 3);
    const unsigned short* gB = B + (size_t)(n0 + rA) * K + ((uA ^ (rA & 7)) << 3);

    // prologue: stage tile 0 (A rows 0-63,64-127; B rows 0-63,64-127,128-191)
    STG_A(0, 0, 0); STG_A(0, 1, 0);
    STG_B(0, 0, 0); STG_B(0, 1, 0); STG_B(0, 2, 0);

    for (int t = 0; t < 16; ++t) {
        const int c = t & 1, nx = c ^ 1;
        const bool more = (t < 15);

        // tile top: current tile's 5 loads complete (issued a full tile ago)
        asm volatile("s_waitcnt vmcnt(0)" ::: "memory");
        __builtin_amdgcn_s_barrier();

        bf16x8 bfr[3][2];
#pragma unroll
        for (int nf = 0; nf < 3; nf++) {
            bfr[nf][0] = LDB(c, nf, 0);
            bfr[nf][1] = LDB(c, nf, 1);
        }

        {   // phase 1: A frags 0-1; issue next B (3 stores)
            bf16x8 a0_ = LDA(c, 0, 0), a1_ = LDA(c, 0, 1);
            bf16x8 a2_ = LDA(c, 1, 0), a3_ = LDA(c, 1, 1);
            if (more) { STG_B(nx, 0, t + 1); STG_B(nx, 1, t + 1); STG_B(nx, 2, t + 1); }
            asm volatile("" ::: "memory");
            __builtin_amdgcn_s_barrier();
            asm volatile("s_waitcnt lgkmcnt(0)");
            MFMA12(0);
        }
        {   // phase 2: A frags 2-3; issue next A (2 stores)
            bf16x8 a0_ = LDA(c, 2, 0), a1_ = LDA(c, 2, 1);
            bf16x8 a2_ = LDA(c, 3, 0), a3_ = LDA(c, 3, 1);
            if (more) { STG_A(nx, 0, t + 1); STG_A(nx, 1, t + 1); }
            asm volatile("" ::: "memory");
            __builtin_amdgcn_s_barrier();
            asm volatile("s_waitcnt lgkmcnt(0)");
            MFMA12(2);
        }
        // next tile-top barrier provides read(c)/overwrite separation
    }

    // ---- epilogue (same mapping family as R15-R18, 128x192 tile) ----
#pragma unroll
    for (int nf = 0; nf < 3; nf++) {
        const int cb = n0 + wn * 48 + nf * 16;
        const int col = cb + a;
        const float bv = bias[col];
        if (cb < 2048) {   // Q/K -> qk buffer (ldc = 2048)
#pragma unroll
            for (int mf = 0; mf < 4; mf++)
#pragma unroll
                for (int jr = 0; jr < 4; jr++) {
                    const int row = m0 + wm * 64 + mf * 16 + g * 4 + jr;
                    qkbuf[(size_t)row * 2048 + col] = f2bf(acc[mf][nf][jr] + bv);
                }
        } else {           // V -> vT[(b*16+h)][d][token], 4-token packs
            const int vd = col - 2048, hh = vd >> 6, dd = vd & 63;
#pragma unroll
            for (int mf = 0; mf < 4; mf++) {
                const int t0 = m0 + wm * 64 + mf * 16 + g * 4;
                const int bb = t0 >> 11, kl = t0 & 2047;
                ushort4v st;
#pragma unroll
                for (int jr = 0; jr < 4; jr++) st[jr] = f2bf(acc[mf][nf][jr] + bv);
                *(ushort4v*)(vT + ((size_t)((bb << 4) + hh) * 64 + dd) * 2048 + kl) = st;
            }
        }
    }
}

// ---------------------------------------------------------------------------
// GEMM2: C[M,N] = A[M,K]*B[N,K]^T + bias[N].  128x128 tile, BK=32, 4 waves.
// 2-PHASE double-buffered LDS (known-good structure; grid 256 = exact fill).
// ---------------------------------------------------------------------------
__global__ void __launch_bounds__(256) gemm_bt(const unsigned short* __restrict__ A,
                                               const unsigned short* __restrict__ B,
                                               const float* __restrict__ bias,
                                               float* __restrict__ C,
                                               int M, int N, int K) {
    __shared__ __attribute__((aligned(16))) unsigned short As[2][128 * 32];
    __shared__ __attribute__((aligned(16))) unsigned short Bs[2][128 * 32];
    const int tid = threadIdx.x;
    const int w = tid >> 6, lane = tid & 63;
    const int a = lane & 15, g = lane >> 4;

    const int cpx = gridDim.x >> 3;
    const int nf = ((int)blockIdx.x & 7) * cpx + ((int)blockIdx.x >> 3);
    const int bx = nf >> 5;
    const int by = nf & 31;
    const int m0 = by * 128, n0 = bx * 128;
    const int wr = (w >> 1) * 64, wc = (w & 1) * 64;

    f32x4 acc[4][4];
#pragma unroll
    for (int i = 0; i < 4; i++)
#pragma unroll
        for (int j = 0; j < 4; j++) acc[i][j] = (f32x4)(0.0f);

    const int r0 = tid >> 2;
    const int c0 = (tid & 3) * 8;
    const unsigned short* gA0 = A + (size_t)(m0 + r0) * K + c0;
    const unsigned short* gA1 = A + (size_t)(m0 + 64 + r0) * K + c0;
    const unsigned short* gB0 = B + (size_t)(n0 + r0) * K + c0;
    const unsigned short* gB1 = B + (size_t)(n0 + 64 + r0) * K + c0;

#define GSTAGE(buf_, k0_)                                               \
    {                                                                   \
        char* la_ = (char*)&As[buf_][0] + w * 1024;                     \
        char* lb_ = (char*)&Bs[buf_][0] + w * 1024;                     \
        GLD16(gA0 + (k0_), la_);                                        \
        GLD16(gA1 + (k0_), la_ + 4096);                                 \
        GLD16(gB0 + (k0_), lb_);                                        \
        GLD16(gB1 + (k0_), lb_ + 4096);                                 \
    }

    GSTAGE(0, 0);
    __syncthreads();

    int cur = 0;
    for (int k0 = 0; k0 < K; k0 += 32) {
        if (k0 + 32 < K) GSTAGE(cur ^ 1, k0 + 32);

        bf16x8 af[4], bfr[4];
#pragma unroll
        for (int i = 0; i < 4; i++) {
            af[i]  = *(const bf16x8*)&As[cur][(wr + i * 16 + a) * 32 + g * 8];
            bfr[i] = *(const bf16x8*)&Bs[cur][(wc + i * 16 + a) * 32 + g * 8];
        }
#pragma unroll
        for (int i = 0; i < 4; i++)
#pragma unroll
            for (int j = 0; j < 4; j++) acc[i][j] = mfma_bf16(af[i], bfr[j], acc[i][j]);

        __syncthreads();
        cur ^= 1;
    }
#undef GSTAGE

#pragma unroll
    for (int j = 0; j < 4; j++) {
        const int col = n0 + wc + j * 16 + a;
        const float bv = bias[col];
#pragma unroll
        for (int i = 0; i < 4; i++)
#pragma unroll
            for (int jr = 0; jr < 4; jr++) {
                const int row = m0 + wr + i * 16 + g * 4 + jr;
                C[(size_t)row * N + col] = acc[i][j][jr] + bv;
            }
    }
}

// ===========================================================================
// Causal flash attention (validated): KVBLK=128, swapped QK^T + in-register
// softmax (exp2 domain), XOR-swizzled double-buffered LDS, setprio clusters.
// ===========================================================================

#define STAGE(bf_, t_)                                                  \
    {                                                                   \
        const size_t ko_ = (size_t)(t_) * 128 * LDQ;                    \
        const size_t vo_ = (size_t)(t_) * 128;                          \
        char* db_ = (char*)&KV[bf_][0] + w * 1024;                      \
        GLD16(sK0 + ko_, db_);                                          \
        GLD16(sK1 + ko_, db_ + 8192);                                   \
        GLD16(sV0 + vo_, db_ + 16384);                                  \
        GLD16(sV1 + vo_, db_ + 24576);                                  \
    }

__global__ void __launch_bounds__(512, 4) attn_fwd(const unsigned short* __restrict__ qk,
                                                   const unsigned short* __restrict__ vT,
                                                   unsigned short* __restrict__ o) {
    constexpr int SL = 2048, DH = 64, LDQ = 2048;
    constexpr float GAMMA = 0.18033688011112042f;  // 0.125 * log2(e)
    const int bh = blockIdx.x & 31;
    const int s = blockIdx.x >> 5;
    const int qb = (s < 8) ? 15 - s : s - 8;
    const int b = bh >> 4, h = bh & 15;
    const int tid = threadIdx.x;
    const int w = tid >> 6, lane = tid & 63;
    const int n = lane & 15, g = lane >> 4;

    __shared__ __attribute__((aligned(16))) unsigned short KV[2][16384];

    const int qs = qb * 128 + w * 16 + n;
    const int nt = qb + 1;

    bf16x8 qf[2];
    {
        const unsigned short* qp = qk + (size_t)(b * SL + qs) * LDQ + h * DH + g * 8;
        short8 la = *(const short8*)qp, lb = *(const short8*)(qp + 32);
        short8 s0, s1;
#pragma unroll
        for (int e = 0; e < 8; e++) {
            s0[e] = (short)f2bf(bf2f((unsigned short)la[e]) * GAMMA);
            s1[e] = (short)f2bf(bf2f((unsigned short)lb[e]) * GAMMA);
        }
        qf[0] = __builtin_bit_cast(bf16x8, s0);
        qf[1] = __builtin_bit_cast(bf16x8, s1);
    }

    const int rK = tid >> 3;
    const int xrK = (rK & 3) | (((rK >> 3) & 1) << 2);
    const int csK = (((tid & 7) ^ xrK) << 3);
    const unsigned short* sK0 = qk + (size_t)(b * SL + rK) * LDQ + 1024 + h * DH + csK;
    const unsigned short* sK1 = sK0 + (size_t)64 * LDQ;
    const int dV = tid >> 4;
    const int csV = (((tid & 15) ^ (dV & 7)) << 3);
    const unsigned short* sV0 = vT + (size_t)bh * DH * SL + (size_t)dV * SL + csV;
    const unsigned short* sV1 = sV0 + (size_t)32 * SL;

    const int srow = 8 * (n >> 2) + (n & 3);
    const int xrq = (n & 3) | (((n >> 2) & 1) << 2);
    const int offK0 = ((g ^ xrq) << 3);
    const int offK1 = offK0 ^ 32;
    int offV[4];
#pragma unroll
    for (int kc = 0; kc < 4; kc++) offV[kc] = (((4 * kc + g) ^ (n & 7)) << 3);

    f32x4 of[4];
#pragma unroll
    for (int i = 0; i < 4; i++) of[i] = (f32x4)(0.0f);
    float m_i = -1e30f, l_i = 0.0f;

    STAGE(0, 0);
    __syncthreads();

    for (int t = 0; t < nt; ++t) {
        const unsigned short* kvb = &KV[t & 1][0];
        if (t + 1 < nt) STAGE((t & 1) ^ 1, t + 1);

        f32x4 p[8];
        __builtin_amdgcn_s_setprio(1);
#pragma unroll
        for (int f = 0; f < 8; f++) {
            const int r_ = srow + ((f >> 1) << 5) + ((f & 1) << 2);
            const bf16x8 ka_ = *(const bf16x8*)&kvb[r_ * 64 + offK0];
            const bf16x8 kc_ = *(const bf16x8*)&kvb[r_ * 64 + offK1];
            f32x4 acc_ = (f32x4)(0.0f);
            acc_ = mfma_bf16(ka_, qf[0], acc_);
            acc_ = mfma_bf16(kc_, qf[1], acc_);
            p[f] = acc_;
        }
        __builtin_amdgcn_s_setprio(0);

        if (t == nt - 1) {
            const int k0 = t * 128;
#pragma unroll
            for (int f = 0; f < 8; f++) {
                const int kb_ = k0 + ((f >> 1) << 5) + ((f & 1) << 2) + 8 * g;
#pragma unroll
                for (int e = 0; e < 4; e++)
                    if (kb_ + e > qs) p[f][e] = -1e30f;
            }
        }

        float mx = -1e30f;
#pragma unroll
        for (int f = 0; f < 8; f++) {
            const float a_ = fmaxf(fmaxf(p[f][0], p[f][1]), fmaxf(p[f][2], p[f][3]));
            mx = fmaxf(mx, a_);
        }
        mx = fmaxf(mx, __shfl_xor(mx, 16));
        mx = fmaxf(mx, __shfl_xor(mx, 32));
        if (!__all(mx <= m_i + 8.0f)) {
            const float mn_ = fmaxf(m_i, mx);
            const float al_ = __builtin_amdgcn_exp2f(m_i - mn_);
            l_i *= al_;
#pragma unroll
            for (int d_ = 0; d_ < 4; d_++) of[d_] = of[d_] * al_;
            m_i = mn_;
        }
        float rs = 0.0f;
#pragma unroll
        for (int f = 0; f < 8; f++)
#pragma unroll
            for (int e = 0; e < 4; e++) {
                p[f][e] = __builtin_amdgcn_exp2f(p[f][e] - m_i);
                rs += p[f][e];
            }
        l_i += rs;

        bf16x8 pf[4];
#pragma unroll
        for (int kc = 0; kc < 4; kc++) {
            uint4v u_;
            u_[0] = pkbf(p[2 * kc][0], p[2 * kc][1]);
            u_[1] = pkbf(p[2 * kc][2], p[2 * kc][3]);
            u_[2] = pkbf(p[2 * kc + 1][0], p[2 * kc + 1][1]);
            u_[3] = pkbf(p[2 * kc + 1][2], p[2 * kc + 1][3]);
            pf[kc] = __builtin_bit_cast(bf16x8, u_);
        }

        const unsigned short* vb = kvb + 8192;
        __builtin_amdgcn_s_setprio(1);
#pragma unroll
        for (int df = 0; df < 4; df++) {
            const int vrow = (df * 16 + n) * 128;
#pragma unroll
            for (int kc = 0; kc < 4; kc++) {
                const bf16x8 va_ = *(const bf16x8*)&vb[vrow + offV[kc]];
                of[df] = mfma_bf16(va_, pf[kc], of[df]);
            }
        }
        __builtin_amdgcn_s_setprio(0);

        __syncthreads();
    }

    float rl = l_i;
    rl += __shfl_xor(rl, 16);
    rl += __shfl_xor(rl, 32);
    const float inv = 1.0f / rl;
    unsigned short* op = o + (size_t)(b * SL + qs) * 1024 + h * DH + 4 * g;
#pragma unroll
    for (int df = 0; df < 4; df++) {
        ushort4v st;
#pragma unroll
        for (int r = 0; r < 4; r++) st[r] = f2bf(of[df][r] * inv);
        *(ushort4v*)(op + df * 16) = st;
    }
}

// ---------------------------------------------------------------------------
extern "C" void kernel_launch(void* const* d_in, const int* in_sizes, int n_in,
                              void* d_out, int out_size, void* d_ws, size_t ws_size,
                              hipStream_t stream) {
    (void)in_sizes; (void)n_in; (void)out_size; (void)ws_size;
    const float* x    = (const float*)d_in[0];
    const float* Wqkv = (const float*)d_in[1];
    const float* bqkv = (const float*)d_in[2];
    const float* Wout = (const float*)d_in[3];
    const float* bout = (const float*)d_in[4];
    float* out = (float*)d_out;

    const int BS = 2, SL = 2048, DM = 1024;
    const int M = BS * SL;   // 4096
    const int K = DM;        // 1024

    // ws layout: x_bf 8M | wqkv_bf 6M | wout_bf 2M | qk 16M | vT 8M | attn_o 8M = 48M
    char* ws = (char*)d_ws;
    unsigned short* x_bf    = (unsigned short*)(ws);
    unsigned short* wqkv_bf = (unsigned short*)(ws + (8u << 20));
    unsigned short* wout_bf = (unsigned short*)(ws + (14u << 20));
    unsigned short* qkbuf   = (unsigned short*)(ws + (16u << 20));
    unsigned short* vTbuf   = (unsigned short*)(ws + (32u << 20));
    unsigned short* attn_o  = (unsigned short*)(ws + (40u << 20));

    cvt_all<<<2048, 256, 0, stream>>>(x, Wqkv, Wout, x_bf, wqkv_bf, wout_bf);

    gemm_qkv<<<dim3(512), 512, 0, stream>>>(x_bf, wqkv_bf, bqkv, qkbuf, vTbuf);

    attn_fwd<<<dim3(512), 512, 0, stream>>>(qkbuf, vTbuf, attn_o);

    gemm_bt<<<dim3(256), 256, 0, stream>>>(attn_o, wout_bf, bout, out, M, DM, K);
}

// Round 20
// 97.957 us; speedup vs baseline: 1.0537x; 1.0155x over previous
//
#include <hip/hip_runtime.h>
#include <cstdint>

typedef __attribute__((ext_vector_type(8))) __bf16 bf16x8;
typedef __attribute__((ext_vector_type(4))) float f32x4;
typedef __attribute__((ext_vector_type(8))) short short8;
typedef __attribute__((ext_vector_type(4))) float float4v;
typedef __attribute__((ext_vector_type(4))) unsigned uint4v;
typedef __attribute__((ext_vector_type(4))) unsigned short ushort4v;

__device__ __forceinline__ unsigned short f2bf(float f) {
    unsigned u = __builtin_bit_cast(unsigned, f);
    u += 0x7fffu + ((u >> 16) & 1u);   // RNE
    return (unsigned short)(u >> 16);
}
__device__ __forceinline__ float bf2f(unsigned short s) {
    return __builtin_bit_cast(float, (unsigned)s << 16);
}
__device__ __forceinline__ f32x4 mfma_bf16(bf16x8 a, bf16x8 b, f32x4 c) {
    return __builtin_amdgcn_mfma_f32_16x16x32_bf16(a, b, c, 0, 0, 0);
}
// pack 2 f32 -> 2 bf16 in one u32 (lo = first arg), RNE
__device__ __forceinline__ unsigned pkbf(float lo, float hi) {
    unsigned r;
    asm("v_cvt_pk_bf16_f32 %0, %1, %2" : "=v"(r) : "v"(lo), "v"(hi));
    return r;
}

#define GLD16(g, l)                                                                     \
    __builtin_amdgcn_global_load_lds((const __attribute__((address_space(1))) void*)(g), \
                                     (__attribute__((address_space(3))) void*)(l), 16, 0, 0)

// ---------------------------------------------------------------------------
// fp32 -> bf16 for ALL THREE arrays in one launch (x | Wqkv | Wout).
// ---------------------------------------------------------------------------
__global__ void __launch_bounds__(256) cvt_all(const float* __restrict__ x,
                                               const float* __restrict__ wqkv,
                                               const float* __restrict__ wout,
                                               unsigned short* __restrict__ xb,
                                               unsigned short* __restrict__ wqb,
                                               unsigned short* __restrict__ wob) {
    int i = blockIdx.x * blockDim.x + threadIdx.x;
#pragma unroll
    for (int k = 0; k < 2; k++, i += 524288) {
        const float* s;
        unsigned short* d;
        int off;
        if (i < 524288)      { s = x;    d = xb;  off = i; }
        else if (i < 917504) { s = wqkv; d = wqb; off = i - 524288; }
        else                 { s = wout; d = wob; off = i - 917504; }
        const float4v* sp = (const float4v*)(s + (size_t)off * 8);
        float4v v0 = sp[0], v1 = sp[1];
        uint4v u;
        u[0] = pkbf(v0[0], v0[1]);
        u[1] = pkbf(v0[2], v0[3]);
        u[2] = pkbf(v1[0], v1[1]);
        u[3] = pkbf(v1[2], v1[3]);
        *(uint4v*)(d + (size_t)off * 8) = u;
    }
}

// ===========================================================================
// GEMM1 (QKV) v19 (KEEP — verified, ~35.5us): phased schedule x co-residency.
// Tile 128x192, BK=64, 8 waves, LDS 80KB -> 2 blocks/CU, grid 512 = exact.
// ===========================================================================

#define STG_A(bf_, i_, t_) \
    GLD16(gA + (size_t)(i_) * 64 * 1024 + (size_t)(t_) * 64, (char*)&Asl[bf_][0] + (i_) * 8192 + w * 1024)
#define STG_B(bf_, i_, t_) \
    GLD16(gB + (size_t)(i_) * 64 * 1024 + (size_t)(t_) * 64, (char*)&Bsl[bf_][0] + (i_) * 8192 + w * 1024)

#define LDA(c_, mf_, kk_) \
    (*(const bf16x8*)((const char*)&Asl[c_][0] + (wm * 64 + (mf_) * 16 + a) * 128 + (((((kk_) << 2) + g) ^ xa) << 4)))
#define LDB(c_, nf_, kk_) \
    (*(const bf16x8*)((const char*)&Bsl[c_][0] + (wn * 48 + (nf_) * 16 + a) * 128 + (((((kk_) << 2) + g) ^ xa) << 4)))

#define MFMA12(mb_)                                                               \
    __builtin_amdgcn_s_setprio(1);                                                \
    _Pragma("unroll") for (int nf_ = 0; nf_ < 3; nf_++) {                         \
        acc[mb_][nf_]       = mfma_bf16(a0_, bfr[nf_][0], acc[mb_][nf_]);         \
        acc[mb_][nf_]       = mfma_bf16(a1_, bfr[nf_][1], acc[mb_][nf_]);         \
        acc[(mb_) + 1][nf_] = mfma_bf16(a2_, bfr[nf_][0], acc[(mb_) + 1][nf_]);   \
        acc[(mb_) + 1][nf_] = mfma_bf16(a3_, bfr[nf_][1], acc[(mb_) + 1][nf_]);   \
    }                                                                             \
    __builtin_amdgcn_s_setprio(0);

__global__ void __launch_bounds__(512, 4) gemm_qkv(const unsigned short* __restrict__ A,
                                                   const unsigned short* __restrict__ B,
                                                   const float* __restrict__ bias,
                                                   unsigned short* __restrict__ qkbuf,
                                                   unsigned short* __restrict__ vT) {
    constexpr int K = 1024;
    __shared__ __attribute__((aligned(16))) unsigned short Asl[2][128 * 64];  // 2x16KB
    __shared__ __attribute__((aligned(16))) unsigned short Bsl[2][192 * 64];  // 2x24KB
    const int tid = threadIdx.x;
    const int w = tid >> 6, lane = tid & 63;
    const int a = lane & 15, g = lane >> 4;
    const int xa = a & 7;
    const int wm = w >> 2, wn = w & 3;

    const int nfb = ((int)blockIdx.x & 7) * 64 + ((int)blockIdx.x >> 3);
    const int bx = nfb >> 5, by = nfb & 31;
    const int m0 = by * 128, n0 = bx * 192;

    f32x4 acc[4][3];
#pragma unroll
    for (int i = 0; i < 4; i++)
#pragma unroll
        for (int j = 0; j < 3; j++) acc[i][j] = (f32x4)(0.0f);

    const int rA = tid >> 3, uA = tid & 7;
    const unsigned short* gA = A + (size_t)(m0 + rA) * K + ((uA ^ (rA & 7)) << 3);
    const unsigned short* gB = B + (size_t)(n0 + rA) * K + ((uA ^ (rA & 7)) << 3);

    STG_A(0, 0, 0); STG_A(0, 1, 0);
    STG_B(0, 0, 0); STG_B(0, 1, 0); STG_B(0, 2, 0);

    for (int t = 0; t < 16; ++t) {
        const int c = t & 1, nx = c ^ 1;
        const bool more = (t < 15);

        asm volatile("s_waitcnt vmcnt(0)" ::: "memory");
        __builtin_amdgcn_s_barrier();

        bf16x8 bfr[3][2];
#pragma unroll
        for (int nf = 0; nf < 3; nf++) {
            bfr[nf][0] = LDB(c, nf, 0);
            bfr[nf][1] = LDB(c, nf, 1);
        }

        {   // phase 1
            bf16x8 a0_ = LDA(c, 0, 0), a1_ = LDA(c, 0, 1);
            bf16x8 a2_ = LDA(c, 1, 0), a3_ = LDA(c, 1, 1);
            if (more) { STG_B(nx, 0, t + 1); STG_B(nx, 1, t + 1); STG_B(nx, 2, t + 1); }
            asm volatile("" ::: "memory");
            __builtin_amdgcn_s_barrier();
            asm volatile("s_waitcnt lgkmcnt(0)");
            MFMA12(0);
        }
        {   // phase 2
            bf16x8 a0_ = LDA(c, 2, 0), a1_ = LDA(c, 2, 1);
            bf16x8 a2_ = LDA(c, 3, 0), a3_ = LDA(c, 3, 1);
            if (more) { STG_A(nx, 0, t + 1); STG_A(nx, 1, t + 1); }
            asm volatile("" ::: "memory");
            __builtin_amdgcn_s_barrier();
            asm volatile("s_waitcnt lgkmcnt(0)");
            MFMA12(2);
        }
    }

#pragma unroll
    for (int nf = 0; nf < 3; nf++) {
        const int cb = n0 + wn * 48 + nf * 16;
        const int col = cb + a;
        const float bv = bias[col];
        if (cb < 2048) {
#pragma unroll
            for (int mf = 0; mf < 4; mf++)
#pragma unroll
                for (int jr = 0; jr < 4; jr++) {
                    const int row = m0 + wm * 64 + mf * 16 + g * 4 + jr;
                    qkbuf[(size_t)row * 2048 + col] = f2bf(acc[mf][nf][jr] + bv);
                }
        } else {
            const int vd = col - 2048, hh = vd >> 6, dd = vd & 63;
#pragma unroll
            for (int mf = 0; mf < 4; mf++) {
                const int t0 = m0 + wm * 64 + mf * 16 + g * 4;
                const int bb = t0 >> 11, kl = t0 & 2047;
                ushort4v st;
#pragma unroll
                for (int jr = 0; jr < 4; jr++) st[jr] = f2bf(acc[mf][nf][jr] + bv);
                *(ushort4v*)(vT + ((size_t)((bb << 4) + hh) * 64 + dd) * 2048 + kl) = st;
            }
        }
    }
}

// ---------------------------------------------------------------------------
// GEMM2 v20: 128x128 tile, BK=32, 2-phase — now 512 thr / 8 WAVES
// (2 waves/SIMD; was 4 waves = 1/SIMD, the worst co-residency in the
// pipeline).  Wave grid 2Mx4N: per-wave 64x32, acc[4][2].  Staging: one
// GLD16 covers a full 8KB tile-half (512 thr x 16B); linear dest w*1024,
// rows tid>>2, cols (tid&3)*8 — same layout as before.
// ---------------------------------------------------------------------------
__global__ void __launch_bounds__(512) gemm_bt(const unsigned short* __restrict__ A,
                                               const unsigned short* __restrict__ B,
                                               const float* __restrict__ bias,
                                               float* __restrict__ C,
                                               int M, int N, int K) {
    __shared__ __attribute__((aligned(16))) unsigned short As[2][128 * 32];
    __shared__ __attribute__((aligned(16))) unsigned short Bs[2][128 * 32];
    const int tid = threadIdx.x;
    const int w = tid >> 6, lane = tid & 63;
    const int a = lane & 15, g = lane >> 4;

    const int cpx = gridDim.x >> 3;
    const int nf = ((int)blockIdx.x & 7) * cpx + ((int)blockIdx.x >> 3);
    const int bx = nf >> 5;          // N-tile (M/128 == 32)
    const int by = nf & 31;          // M-tile
    const int m0 = by * 128, n0 = bx * 128;
    const int wr = (w >> 2) * 64, wc = (w & 3) * 32;

    f32x4 acc[4][2];
#pragma unroll
    for (int i = 0; i < 4; i++)
#pragma unroll
        for (int j = 0; j < 2; j++) acc[i][j] = (f32x4)(0.0f);

    const int r0 = tid >> 2;         // 0..127
    const int c0 = (tid & 3) * 8;
    const unsigned short* gA0 = A + (size_t)(m0 + r0) * K + c0;
    const unsigned short* gB0 = B + (size_t)(n0 + r0) * K + c0;

#define GSTAGE(buf_, k0_)                                               \
    {                                                                   \
        GLD16(gA0 + (k0_), (char*)&As[buf_][0] + w * 1024);             \
        GLD16(gB0 + (k0_), (char*)&Bs[buf_][0] + w * 1024);             \
    }

    GSTAGE(0, 0);
    __syncthreads();

    int cur = 0;
    for (int k0 = 0; k0 < K; k0 += 32) {
        if (k0 + 32 < K) GSTAGE(cur ^ 1, k0 + 32);

        bf16x8 af[4], bfr[2];
#pragma unroll
        for (int i = 0; i < 4; i++)
            af[i] = *(const bf16x8*)&As[cur][(wr + i * 16 + a) * 32 + g * 8];
#pragma unroll
        for (int j = 0; j < 2; j++)
            bfr[j] = *(const bf16x8*)&Bs[cur][(wc + j * 16 + a) * 32 + g * 8];
        __builtin_amdgcn_s_setprio(1);
#pragma unroll
        for (int i = 0; i < 4; i++)
#pragma unroll
            for (int j = 0; j < 2; j++) acc[i][j] = mfma_bf16(af[i], bfr[j], acc[i][j]);
        __builtin_amdgcn_s_setprio(0);

        __syncthreads();
        cur ^= 1;
    }
#undef GSTAGE

#pragma unroll
    for (int j = 0; j < 2; j++) {
        const int col = n0 + wc + j * 16 + a;
        const float bv = bias[col];
#pragma unroll
        for (int i = 0; i < 4; i++)
#pragma unroll
            for (int jr = 0; jr < 4; jr++) {
                const int row = m0 + wr + i * 16 + g * 4 + jr;
                C[(size_t)row * N + col] = acc[i][j][jr] + bv;
            }
    }
}

// ===========================================================================
// Causal flash attention (validated): KVBLK=128, swapped QK^T + in-register
// softmax (exp2 domain), XOR-swizzled double-buffered LDS, setprio clusters.
// ===========================================================================

#define STAGE(bf_, t_)                                                  \
    {                                                                   \
        const size_t ko_ = (size_t)(t_) * 128 * LDQ;                    \
        const size_t vo_ = (size_t)(t_) * 128;                          \
        char* db_ = (char*)&KV[bf_][0] + w * 1024;                      \
        GLD16(sK0 + ko_, db_);                                          \
        GLD16(sK1 + ko_, db_ + 8192);                                   \
        GLD16(sV0 + vo_, db_ + 16384);                                  \
        GLD16(sV1 + vo_, db_ + 24576);                                  \
    }

__global__ void __launch_bounds__(512, 4) attn_fwd(const unsigned short* __restrict__ qk,
                                                   const unsigned short* __restrict__ vT,
                                                   unsigned short* __restrict__ o) {
    constexpr int SL = 2048, DH = 64, LDQ = 2048;
    constexpr float GAMMA = 0.18033688011112042f;  // 0.125 * log2(e)
    const int bh = blockIdx.x & 31;
    const int s = blockIdx.x >> 5;
    const int qb = (s < 8) ? 15 - s : s - 8;
    const int b = bh >> 4, h = bh & 15;
    const int tid = threadIdx.x;
    const int w = tid >> 6, lane = tid & 63;
    const int n = lane & 15, g = lane >> 4;

    __shared__ __attribute__((aligned(16))) unsigned short KV[2][16384];

    const int qs = qb * 128 + w * 16 + n;
    const int nt = qb + 1;

    bf16x8 qf[2];
    {
        const unsigned short* qp = qk + (size_t)(b * SL + qs) * LDQ + h * DH + g * 8;
        short8 la = *(const short8*)qp, lb = *(const short8*)(qp + 32);
        short8 s0, s1;
#pragma unroll
        for (int e = 0; e < 8; e++) {
            s0[e] = (short)f2bf(bf2f((unsigned short)la[e]) * GAMMA);
            s1[e] = (short)f2bf(bf2f((unsigned short)lb[e]) * GAMMA);
        }
        qf[0] = __builtin_bit_cast(bf16x8, s0);
        qf[1] = __builtin_bit_cast(bf16x8, s1);
    }

    const int rK = tid >> 3;
    const int xrK = (rK & 3) | (((rK >> 3) & 1) << 2);
    const int csK = (((tid & 7) ^ xrK) << 3);
    const unsigned short* sK0 = qk + (size_t)(b * SL + rK) * LDQ + 1024 + h * DH + csK;
    const unsigned short* sK1 = sK0 + (size_t)64 * LDQ;
    const int dV = tid >> 4;
    const int csV = (((tid & 15) ^ (dV & 7)) << 3);
    const unsigned short* sV0 = vT + (size_t)bh * DH * SL + (size_t)dV * SL + csV;
    const unsigned short* sV1 = sV0 + (size_t)32 * SL;

    const int srow = 8 * (n >> 2) + (n & 3);
    const int xrq = (n & 3) | (((n >> 2) & 1) << 2);
    const int offK0 = ((g ^ xrq) << 3);
    const int offK1 = offK0 ^ 32;
    int offV[4];
#pragma unroll
    for (int kc = 0; kc < 4; kc++) offV[kc] = (((4 * kc + g) ^ (n & 7)) << 3);

    f32x4 of[4];
#pragma unroll
    for (int i = 0; i < 4; i++) of[i] = (f32x4)(0.0f);
    float m_i = -1e30f, l_i = 0.0f;

    STAGE(0, 0);
    __syncthreads();

    for (int t = 0; t < nt; ++t) {
        const unsigned short* kvb = &KV[t & 1][0];
        if (t + 1 < nt) STAGE((t & 1) ^ 1, t + 1);

        f32x4 p[8];
        __builtin_amdgcn_s_setprio(1);
#pragma unroll
        for (int f = 0; f < 8; f++) {
            const int r_ = srow + ((f >> 1) << 5) + ((f & 1) << 2);
            const bf16x8 ka_ = *(const bf16x8*)&kvb[r_ * 64 + offK0];
            const bf16x8 kc_ = *(const bf16x8*)&kvb[r_ * 64 + offK1];
            f32x4 acc_ = (f32x4)(0.0f);
            acc_ = mfma_bf16(ka_, qf[0], acc_);
            acc_ = mfma_bf16(kc_, qf[1], acc_);
            p[f] = acc_;
        }
        __builtin_amdgcn_s_setprio(0);

        if (t == nt - 1) {
            const int k0 = t * 128;
#pragma unroll
            for (int f = 0; f < 8; f++) {
                const int kb_ = k0 + ((f >> 1) << 5) + ((f & 1) << 2) + 8 * g;
#pragma unroll
                for (int e = 0; e < 4; e++)
                    if (kb_ + e > qs) p[f][e] = -1e30f;
            }
        }

        float mx = -1e30f;
#pragma unroll
        for (int f = 0; f < 8; f++) {
            const float a_ = fmaxf(fmaxf(p[f][0], p[f][1]), fmaxf(p[f][2], p[f][3]));
            mx = fmaxf(mx, a_);
        }
        mx = fmaxf(mx, __shfl_xor(mx, 16));
        mx = fmaxf(mx, __shfl_xor(mx, 32));
        if (!__all(mx <= m_i + 8.0f)) {
            const float mn_ = fmaxf(m_i, mx);
            const float al_ = __builtin_amdgcn_exp2f(m_i - mn_);
            l_i *= al_;
#pragma unroll
            for (int d_ = 0; d_ < 4; d_++) of[d_] = of[d_] * al_;
            m_i = mn_;
        }
        float rs = 0.0f;
#pragma unroll
        for (int f = 0; f < 8; f++)
#pragma unroll
            for (int e = 0; e < 4; e++) {
                p[f][e] = __builtin_amdgcn_exp2f(p[f][e] - m_i);
                rs += p[f][e];
            }
        l_i += rs;

        bf16x8 pf[4];
#pragma unroll
        for (int kc = 0; kc < 4; kc++) {
            uint4v u_;
            u_[0] = pkbf(p[2 * kc][0], p[2 * kc][1]);
            u_[1] = pkbf(p[2 * kc][2], p[2 * kc][3]);
            u_[2] = pkbf(p[2 * kc + 1][0], p[2 * kc + 1][1]);
            u_[3] = pkbf(p[2 * kc + 1][2], p[2 * kc + 1][3]);
            pf[kc] = __builtin_bit_cast(bf16x8, u_);
        }

        const unsigned short* vb = kvb + 8192;
        __builtin_amdgcn_s_setprio(1);
#pragma unroll
        for (int df = 0; df < 4; df++) {
            const int vrow = (df * 16 + n) * 128;
#pragma unroll
            for (int kc = 0; kc < 4; kc++) {
                const bf16x8 va_ = *(const bf16x8*)&vb[vrow + offV[kc]];
                of[df] = mfma_bf16(va_, pf[kc], of[df]);
            }
        }
        __builtin_amdgcn_s_setprio(0);

        __syncthreads();
    }

    float rl = l_i;
    rl += __shfl_xor(rl, 16);
    rl += __shfl_xor(rl, 32);
    const float inv = 1.0f / rl;
    unsigned short* op = o + (size_t)(b * SL + qs) * 1024 + h * DH + 4 * g;
#pragma unroll
    for (int df = 0; df < 4; df++) {
        ushort4v st;
#pragma unroll
        for (int r = 0; r < 4; r++) st[r] = f2bf(of[df][r] * inv);
        *(ushort4v*)(op + df * 16) = st;
    }
}

// ---------------------------------------------------------------------------
extern "C" void kernel_launch(void* const* d_in, const int* in_sizes, int n_in,
                              void* d_out, int out_size, void* d_ws, size_t ws_size,
                              hipStream_t stream) {
    (void)in_sizes; (void)n_in; (void)out_size; (void)ws_size;
    const float* x    = (const float*)d_in[0];
    const float* Wqkv = (const float*)d_in[1];
    const float* bqkv = (const float*)d_in[2];
    const float* Wout = (const float*)d_in[3];
    const float* bout = (const float*)d_in[4];
    float* out = (float*)d_out;

    const int BS = 2, SL = 2048, DM = 1024;
    const int M = BS * SL;   // 4096
    const int K = DM;        // 1024

    // ws layout: x_bf 8M | wqkv_bf 6M | wout_bf 2M | qk 16M | vT 8M | attn_o 8M = 48M
    char* ws = (char*)d_ws;
    unsigned short* x_bf    = (unsigned short*)(ws);
    unsigned short* wqkv_bf = (unsigned short*)(ws + (8u << 20));
    unsigned short* wout_bf = (unsigned short*)(ws + (14u << 20));
    unsigned short* qkbuf   = (unsigned short*)(ws + (16u << 20));
    unsigned short* vTbuf   = (unsigned short*)(ws + (32u << 20));
    unsigned short* attn_o  = (unsigned short*)(ws + (40u << 20));

    cvt_all<<<2048, 256, 0, stream>>>(x, Wqkv, Wout, x_bf, wqkv_bf, wout_bf);

    gemm_qkv<<<dim3(512), 512, 0, stream>>>(x_bf, wqkv_bf, bqkv, qkbuf, vTbuf);

    attn_fwd<<<dim3(512), 512, 0, stream>>>(qkbuf, vTbuf, attn_o);

    gemm_bt<<<dim3(256), 512, 0, stream>>>(attn_o, wout_bf, bout, out, M, DM, K);
}